// Round 13
// baseline (1505.918 us; speedup 1.0000x reference)
//
#include <hip/hip_runtime.h>
#include <stdint.h>

#define BB 2
#define NQ 4096
#define NK 8192
#define DD 512
#define HH 4
#define TOPK 64

typedef unsigned int u32;
typedef unsigned long long u64;

// 2-accumulator k-unrolled FMA kernel model (MKL/oneDNN-style latency hiding):
// acc0 accumulates k = 0,2,4,...; acc1 accumulates k = 1,3,5,...; single
// combining add at the end. No K-blocking (one panel).
__device__ __forceinline__ float dot512(const float* __restrict__ x,
                                        const float* __restrict__ w) {
#pragma clang fp contract(off)
    const float4* xr = (const float4*)x;
    const float4* wr = (const float4*)w;
    float acc0 = 0.f, acc1 = 0.f;
#pragma unroll 8
    for (int j = 0; j < DD / 4; ++j) {
        float4 a = xr[j], b = wr[j];
        acc0 = fmaf(a.x, b.x, acc0);   // k = 4j   (even)
        acc1 = fmaf(a.y, b.y, acc1);   // k = 4j+1 (odd)
        acc0 = fmaf(a.z, b.z, acc0);   // k = 4j+2 (even)
        acc1 = fmaf(a.w, b.w, acc1);   // k = 4j+3 (odd)
    }
    return acc0 + acc1;  // single combine rounding
}

// Pass 1: projection + per-(type,b,h) absmax via atomicMax on f32 bits.
__global__ __launch_bounds__(256) void proj_absmax_kernel(
        const float* __restrict__ query, const float* __restrict__ key,
        const float* __restrict__ Wq, const float* __restrict__ Wk,
        u32* __restrict__ scale_bits) {
#pragma clang fp contract(off)
    const int nq = BB * NQ * 32;
    int gid = blockIdx.x * 256 + threadIdx.x;
    int type = (gid >= nq);
    int idx = type ? gid - nq : gid;
    const float* X = type ? key : query;
    const float* W = type ? Wk : Wq;
    int o = idx & 31, row = idx >> 5;
    int h = o >> 3;
    int b = type ? (idx >> 18) : (idx >> 17);
    float v = dot512(X + (size_t)row * DD, W + (size_t)o * DD);
    u32 bits = __float_as_uint(fabsf(v));
    __shared__ u32 lmax[4];
    if (threadIdx.x < 4) lmax[threadIdx.x] = 0u;
    __syncthreads();
    atomicMax(&lmax[h], bits);
    __syncthreads();
    if (threadIdx.x < 4)  // type/b uniform per block (boundaries multiple of 256)
        atomicMax(&scale_bits[type * 8 + b * 4 + threadIdx.x], lmax[threadIdx.x]);
}

// Pass 2: recompute identical projection, quantize to int8 (round-half-even).
__global__ __launch_bounds__(256) void proj_quant_kernel(
        const float* __restrict__ query, const float* __restrict__ key,
        const float* __restrict__ Wq, const float* __restrict__ Wk,
        const u32* __restrict__ scale_bits,
        char* __restrict__ q8, char* __restrict__ k8) {
#pragma clang fp contract(off)
    const int nq = BB * NQ * 32;
    int gid = blockIdx.x * 256 + threadIdx.x;
    int type = (gid >= nq);
    int idx = type ? gid - nq : gid;
    const float* X = type ? key : query;
    const float* W = type ? Wk : Wq;
    int o = idx & 31, row = idx >> 5;
    int h = o >> 3;
    int b = type ? (idx >> 18) : (idx >> 17);
    float v = dot512(X + (size_t)row * DD, W + (size_t)o * DD);
    float mx = __uint_as_float(scale_bits[type * 8 + b * 4 + h]);
    float scale = (mx + 1e-6f) / 127.0f;
    float r = rintf(v / scale);  // round-half-to-even
    r = fminf(fmaxf(r, -127.f), 127.f);
    (type ? k8 : q8)[idx] = (char)(int)r;
}

__device__ __forceinline__ int bdot4(u32 a, u32 b, int acc) {
    acc += (int)(signed char)(a & 0xFF) * (int)(signed char)(b & 0xFF);
    acc += (int)(signed char)((a >> 8) & 0xFF) * (int)(signed char)((b >> 8) & 0xFF);
    acc += (int)(signed char)((a >> 16) & 0xFF) * (int)(signed char)((b >> 16) & 0xFF);
    acc += (int)(signed char)((a >> 24) & 0xFF) * (int)(signed char)((b >> 24) & 0xFF);
    return acc;
}

// ---------------- fused scores (f32, contract-off epilogue) + EXACT top-64 ----------------
__global__ __launch_bounds__(256) void score_topk_kernel(
    const char* __restrict__ q8, const char* __restrict__ k8,
    const u32* __restrict__ scale_bits, const float* __restrict__ w,
    int* __restrict__ out) {
#pragma clang fp contract(off)
    __shared__ u64 keys[NK];  // 64 KB
    __shared__ u64 redS[4];

    const int row = blockIdx.x;  // b*NQ + qi
    const int b = row >> 12;
    const int t = threadIdx.x;

    const u32* qr = (const u32*)(q8 + (size_t)row * 32);
    u32 qa[8];
#pragma unroll
    for (int j = 0; j < 8; ++j) qa[j] = qr[j];

    float ts[HH], wt[HH];
#pragma unroll
    for (int h = 0; h < HH; ++h) {
        float qs = (__uint_as_float(scale_bits[b * 4 + h]) + 1e-6f) / 127.0f;
        float ks = (__uint_as_float(scale_bits[8 + b * 4 + h]) + 1e-6f) / 127.0f;
        ts[h] = qs * ks;  // total_scale
        wt[h] = w[h];
    }

    const u32* kbase = (const u32*)(k8 + (size_t)b * NK * 32);
    for (int i = 0; i < NK / 256; ++i) {
        int n = t + i * 256;
        const u32* kr = kbase + (size_t)n * 8;
        u32 ka[8];
        *(uint4*)(ka) = *(const uint4*)(kr);
        *(uint4*)(ka + 4) = *(const uint4*)(kr + 4);
        float acc = 0.f;
#pragma unroll
        for (int h = 0; h < HH; ++h) {
            int s = 0;
            s = bdot4(qa[h * 2 + 0], ka[h * 2 + 0], s);
            s = bdot4(qa[h * 2 + 1], ka[h * 2 + 1], s);
            float sf = (float)s * ts[h];   // mul (rounds)
            sf = fmaxf(sf, 0.f);           // relu
            float prod = sf * wt[h];       // separate mul
            acc = acc + prod;              // separate add, sequential h
        }
        acc = acc + 0.0f;  // canonicalize -0 -> +0
        u32 u = __float_as_uint(acc);
        u = (u & 0x80000000u) ? ~u : (u | 0x80000000u);  // monotonic map
        keys[n] = ((u64)u << 32) | (u64)(0xFFFFFFFFu - (u32)n);  // ties: LOWER index wins
    }
    __syncthreads();

    // 64 rounds of exact block-wide argmax.
    for (int r = 0; r < TOPK; ++r) {
        u64 m = 0ull;
#pragma unroll
        for (int i = 0; i < NK / 256; ++i) {
            u64 kk = keys[t + i * 256];
            m = (kk > m) ? kk : m;
        }
#pragma unroll
        for (int off = 32; off > 0; off >>= 1) {
            u64 o = __shfl_down(m, off, 64);
            m = (o > m) ? o : m;
        }
        if ((t & 63) == 0) { redS[t >> 6] = m; }
        __syncthreads();
        if (t == 0) {
            u64 a0 = redS[0] > redS[1] ? redS[0] : redS[1];
            u64 a1 = redS[2] > redS[3] ? redS[2] : redS[3];
            u64 bs = a0 > a1 ? a0 : a1;
            u32 n = 0xFFFFFFFFu - (u32)bs;
            keys[n] = 0ull;  // remove winner
            out[(size_t)row * TOPK + r] = (int)n;
        }
        __syncthreads();
    }
}

extern "C" void kernel_launch(void* const* d_in, const int* in_sizes, int n_in,
                              void* d_out, int out_size, void* d_ws, size_t ws_size,
                              hipStream_t stream) {
    const float* query = (const float*)d_in[0];
    const float* key = (const float*)d_in[1];
    const float* Wq = (const float*)d_in[2];
    const float* Wk = (const float*)d_in[3];
    const float* ow = (const float*)d_in[4];

    char* ws = (char*)d_ws;
    u32* scale_bits = (u32*)ws;
    char* q8 = ws + 1024;
    char* k8 = q8 + BB * NQ * 32;
    int* out = (int*)d_out;

    hipMemsetAsync(scale_bits, 0, 64, stream);

    const int total_elems = BB * (NQ + NK) * 32;  // 786432
    proj_absmax_kernel<<<total_elems / 256, 256, 0, stream>>>(query, key, Wq, Wk, scale_bits);
    proj_quant_kernel<<<total_elems / 256, 256, 0, stream>>>(query, key, Wq, Wk, scale_bits, q8, k8);
    score_topk_kernel<<<BB * NQ, 256, 0, stream>>>(q8, k8, scale_bits, ow, out);
}

// Round 14
// 1059.102 us; speedup vs baseline: 1.4219x; 1.4219x over previous
//
#include <hip/hip_runtime.h>
#include <stdint.h>

#define BB 2
#define NQ 4096
#define NK 8192
#define DD 512
#define HH 4
#define TOPK 64

typedef unsigned int u32;
typedef unsigned long long u64;

#if defined(__has_builtin)
#if __has_builtin(__builtin_amdgcn_sdot4)
#define HAVE_SDOT4 1
#endif
#endif

// Exact int8x4 dot (int32 accumulate) — identical math to manual unpack.
__device__ __forceinline__ int dot4i8(u32 a, u32 b, int acc) {
#ifdef HAVE_SDOT4
    return __builtin_amdgcn_sdot4((int)a, (int)b, acc, false);
#else
    acc += (int)(signed char)(a & 0xFF) * (int)(signed char)(b & 0xFF);
    acc += (int)(signed char)((a >> 8) & 0xFF) * (int)(signed char)((b >> 8) & 0xFF);
    acc += (int)(signed char)((a >> 16) & 0xFF) * (int)(signed char)((b >> 16) & 0xFF);
    acc += (int)(signed char)((a >> 24) & 0xFF) * (int)(signed char)((b >> 24) & 0xFF);
    return acc;
#endif
}

// ---- GOLDEN projection structure (DO NOT TOUCH): 2-accumulator interleaved
// FMA chains (even/odd k), one combining add. Verified bit-exact vs reference
// (round 13: absmax 0.0).
__device__ __forceinline__ float dot512(const float* __restrict__ x,
                                        const float* __restrict__ w) {
#pragma clang fp contract(off)
    const float4* xr = (const float4*)x;
    const float4* wr = (const float4*)w;
    float acc0 = 0.f, acc1 = 0.f;
#pragma unroll 8
    for (int j = 0; j < DD / 4; ++j) {
        float4 a = xr[j], b = wr[j];
        acc0 = fmaf(a.x, b.x, acc0);
        acc1 = fmaf(a.y, b.y, acc1);
        acc0 = fmaf(a.z, b.z, acc0);
        acc1 = fmaf(a.w, b.w, acc1);
    }
    return acc0 + acc1;
}

// Pass 1: projection + per-(type,b,h) absmax via atomicMax on f32 bits.
__global__ __launch_bounds__(256) void proj_absmax_kernel(
        const float* __restrict__ query, const float* __restrict__ key,
        const float* __restrict__ Wq, const float* __restrict__ Wk,
        u32* __restrict__ scale_bits) {
#pragma clang fp contract(off)
    const int nq = BB * NQ * 32;
    int gid = blockIdx.x * 256 + threadIdx.x;
    int type = (gid >= nq);
    int idx = type ? gid - nq : gid;
    const float* X = type ? key : query;
    const float* W = type ? Wk : Wq;
    int o = idx & 31, row = idx >> 5;
    int h = o >> 3;
    int b = type ? (idx >> 18) : (idx >> 17);
    float v = dot512(X + (size_t)row * DD, W + (size_t)o * DD);
    u32 bits = __float_as_uint(fabsf(v));
    __shared__ u32 lmax[4];
    if (threadIdx.x < 4) lmax[threadIdx.x] = 0u;
    __syncthreads();
    atomicMax(&lmax[h], bits);
    __syncthreads();
    if (threadIdx.x < 4)
        atomicMax(&scale_bits[type * 8 + b * 4 + threadIdx.x], lmax[threadIdx.x]);
}

// Pass 2: recompute identical projection, quantize to int8 (round-half-even).
__global__ __launch_bounds__(256) void proj_quant_kernel(
        const float* __restrict__ query, const float* __restrict__ key,
        const float* __restrict__ Wq, const float* __restrict__ Wk,
        const u32* __restrict__ scale_bits,
        char* __restrict__ q8, char* __restrict__ k8) {
#pragma clang fp contract(off)
    const int nq = BB * NQ * 32;
    int gid = blockIdx.x * 256 + threadIdx.x;
    int type = (gid >= nq);
    int idx = type ? gid - nq : gid;
    const float* X = type ? key : query;
    const float* W = type ? Wk : Wq;
    int o = idx & 31, row = idx >> 5;
    int h = o >> 3;
    int b = type ? (idx >> 18) : (idx >> 17);
    float v = dot512(X + (size_t)row * DD, W + (size_t)o * DD);
    float mx = __uint_as_float(scale_bits[type * 8 + b * 4 + h]);
    float scale = (mx + 1e-6f) / 127.0f;
    float r = rintf(v / scale);
    r = fminf(fmaxf(r, -127.f), 127.f);
    (type ? k8 : q8)[idx] = (char)(int)r;
}

// ---------------- fused scores + EXACT top-64, register-resident keys ----------------
// Keys live in VGPRs (32 u64/thread, statically unrolled). Each round:
// 6-step u64 wave shuffle-max of cached per-thread maxes + 4-way LDS merge;
// only the winner's owner rescans its registers. 2 barriers/round, 32 B LDS.
__global__ __launch_bounds__(256) void score_topk_kernel(
    const char* __restrict__ q8, const char* __restrict__ k8,
    const u32* __restrict__ scale_bits, const float* __restrict__ w,
    int* __restrict__ out) {
#pragma clang fp contract(off)
    __shared__ u64 wmax[4];

    const int row = blockIdx.x;  // b*NQ + qi
    const int b = row >> 12;
    const int t = threadIdx.x;
    const int wv = t >> 6;

    const u32* qr = (const u32*)(q8 + (size_t)row * 32);
    u32 qa[8];
#pragma unroll
    for (int j = 0; j < 8; ++j) qa[j] = qr[j];

    float ts[HH], wt[HH];
#pragma unroll
    for (int h = 0; h < HH; ++h) {
        float qs = (__uint_as_float(scale_bits[b * 4 + h]) + 1e-6f) / 127.0f;
        float ks = (__uint_as_float(scale_bits[8 + b * 4 + h]) + 1e-6f) / 127.0f;
        ts[h] = qs * ks;  // total_scale
        wt[h] = w[h];
    }

    const u32* kbase = (const u32*)(k8 + (size_t)b * NK * 32);
    u64 key[32];
#pragma unroll
    for (int i = 0; i < 32; ++i) {
        int n = t + i * 256;
        const u32* kr = kbase + (size_t)n * 8;
        uint4 k0 = *(const uint4*)(kr);
        uint4 k1 = *(const uint4*)(kr + 4);
        float acc = 0.f;
        {   // h = 0
            int s = dot4i8(qa[0], k0.x, 0); s = dot4i8(qa[1], k0.y, s);
            float sf = (float)s * ts[0]; sf = fmaxf(sf, 0.f);
            float prod = sf * wt[0]; acc = acc + prod;
        }
        {   // h = 1
            int s = dot4i8(qa[2], k0.z, 0); s = dot4i8(qa[3], k0.w, s);
            float sf = (float)s * ts[1]; sf = fmaxf(sf, 0.f);
            float prod = sf * wt[1]; acc = acc + prod;
        }
        {   // h = 2
            int s = dot4i8(qa[4], k1.x, 0); s = dot4i8(qa[5], k1.y, s);
            float sf = (float)s * ts[2]; sf = fmaxf(sf, 0.f);
            float prod = sf * wt[2]; acc = acc + prod;
        }
        {   // h = 3
            int s = dot4i8(qa[6], k1.z, 0); s = dot4i8(qa[7], k1.w, s);
            float sf = (float)s * ts[3]; sf = fmaxf(sf, 0.f);
            float prod = sf * wt[3]; acc = acc + prod;
        }
        acc = acc + 0.0f;  // canonicalize -0 -> +0
        u32 u = __float_as_uint(acc);
        u = (u & 0x80000000u) ? ~u : (u | 0x80000000u);  // monotonic map
        key[i] = ((u64)u << 32) | (u64)(0xFFFFFFFFu - (u32)n);  // ties: LOWER index wins
    }

    // cached per-thread max
    u64 lmax = key[0];
#pragma unroll
    for (int i = 1; i < 32; ++i) lmax = key[i] > lmax ? key[i] : lmax;

    for (int r = 0; r < TOPK; ++r) {
        // wave-level shuffle max
        u64 m = lmax;
#pragma unroll
        for (int off = 32; off > 0; off >>= 1) {
            u64 o = __shfl_down(m, off, 64);
            m = o > m ? o : m;
        }
        if ((t & 63) == 0) wmax[wv] = m;
        __syncthreads();
        u64 g0 = wmax[0] > wmax[1] ? wmax[0] : wmax[1];
        u64 g1 = wmax[2] > wmax[3] ? wmax[2] : wmax[3];
        u64 gm = g0 > g1 ? g0 : g1;
        u32 n = 0xFFFFFFFFu - (u32)gm;
        if (t == 0) out[(size_t)row * TOPK + r] = (int)n;
        if ((int)(n & 255u) == t) {  // owner: clear winner, refresh cached max
            int slot = (int)(n >> 8);
#pragma unroll
            for (int i = 0; i < 32; ++i)
                if (i == slot) key[i] = 0ull;
            lmax = key[0];
#pragma unroll
            for (int i = 1; i < 32; ++i) lmax = key[i] > lmax ? key[i] : lmax;
        }
        __syncthreads();  // WAR on wmax before next round
    }
}

extern "C" void kernel_launch(void* const* d_in, const int* in_sizes, int n_in,
                              void* d_out, int out_size, void* d_ws, size_t ws_size,
                              hipStream_t stream) {
    const float* query = (const float*)d_in[0];
    const float* key = (const float*)d_in[1];
    const float* Wq = (const float*)d_in[2];
    const float* Wk = (const float*)d_in[3];
    const float* ow = (const float*)d_in[4];

    char* ws = (char*)d_ws;
    u32* scale_bits = (u32*)ws;
    char* q8 = ws + 1024;
    char* k8 = q8 + BB * NQ * 32;
    int* out = (int*)d_out;

    hipMemsetAsync(scale_bits, 0, 64, stream);

    const int total_elems = BB * (NQ + NK) * 32;  // 786432
    proj_absmax_kernel<<<total_elems / 256, 256, 0, stream>>>(query, key, Wq, Wk, scale_bits);
    proj_quant_kernel<<<total_elems / 256, 256, 0, stream>>>(query, key, Wq, Wk, scale_bits, q8, k8);
    score_topk_kernel<<<BB * NQ, 256, 0, stream>>>(q8, k8, scale_bits, ow, out);
}

// Round 15
// 712.274 us; speedup vs baseline: 2.1142x; 1.4869x over previous
//
#include <hip/hip_runtime.h>
#include <stdint.h>

#define BB 2
#define NQ 4096
#define NK 8192
#define DD 512
#define HH 4
#define TOPK 64

typedef unsigned int u32;
typedef unsigned long long u64;

#if defined(__has_builtin)
#if __has_builtin(__builtin_amdgcn_sdot4)
#define HAVE_SDOT4 1
#endif
#endif

__device__ __forceinline__ int dot4i8(u32 a, u32 b, int acc) {
#ifdef HAVE_SDOT4
    return __builtin_amdgcn_sdot4((int)a, (int)b, acc, false);
#else
    acc += (int)(signed char)(a & 0xFF) * (int)(signed char)(b & 0xFF);
    acc += (int)(signed char)((a >> 8) & 0xFF) * (int)(signed char)((b >> 8) & 0xFF);
    acc += (int)(signed char)((a >> 16) & 0xFF) * (int)(signed char)((b >> 16) & 0xFF);
    acc += (int)(signed char)((a >> 24) & 0xFF) * (int)(signed char)((b >> 24) & 0xFF);
    return acc;
#endif
}

// ---- GOLDEN accumulation order (verified bit-exact, round 13): 2-accumulator
// interleaved FMA chains (even/odd within each float4), one combining add.
// The staging below only changes WHERE values are read from, never the order.

// Shared staging layout: 16 rows x 16 outputs per 256-thread block.
//   xs[lr][j]   : row-major float4 of x rows (16 x 128 float4 = 32 KB)
//   wl[j][o16]  : transposed W tile (128 x 16 float4 = 32 KB) -> conflict-free
#define PROJ_BODY(EMIT)                                                          \
    __shared__ float4 xs[16][128];                                               \
    __shared__ float4 wl[128][16];                                               \
    const int nqrows = BB * NQ;                                                  \
    int blk = blockIdx.x;                                                        \
    int half = blk & 1;                                                          \
    int row0 = (blk >> 1) << 4;                                                  \
    int type = (row0 >= nqrows);                                                 \
    int trow0 = type ? row0 - nqrows : row0;                                     \
    int b = type ? (trow0 >> 13) : (trow0 >> 12);                                \
    const float* X = type ? key : query;                                         \
    const float* W = type ? Wk : Wq;                                             \
    const int t = threadIdx.x;                                                   \
    {                                                                            \
        const float4* xg = (const float4*)(X + (size_t)trow0 * DD);              \
        float4* xsf = &xs[0][0];                                                 \
        for (int i = t; i < 2048; i += 256) xsf[i] = xg[i];                      \
        const float4* wg = (const float4*)W;                                     \
        for (int i = t; i < 2048; i += 256) {                                    \
            int oo = i & 15, jj = i >> 4;                                        \
            wl[jj][oo] = wg[(size_t)(half * 16 + oo) * 128 + jj];                \
        }                                                                        \
    }                                                                            \
    __syncthreads();                                                             \
    int o16 = t & 15, lr = t >> 4;                                               \
    int o = half * 16 + o16;                                                     \
    int h = o >> 3;                                                              \
    int trow = trow0 + lr;                                                       \
    float acc0 = 0.f, acc1 = 0.f;                                                \
    _Pragma("unroll 8")                                                          \
    for (int j = 0; j < 128; ++j) {                                              \
        float4 a = xs[lr][j];                                                    \
        float4 bb = wl[j][o16];                                                  \
        acc0 = fmaf(a.x, bb.x, acc0);                                            \
        acc1 = fmaf(a.y, bb.y, acc1);                                            \
        acc0 = fmaf(a.z, bb.z, acc0);                                            \
        acc1 = fmaf(a.w, bb.w, acc1);                                            \
    }                                                                            \
    float v = acc0 + acc1;                                                       \
    EMIT

// Pass 1: projection + per-(type,b,h) absmax via atomicMax on f32 bits.
__global__ __launch_bounds__(256, 2) void proj_absmax_kernel(
        const float* __restrict__ query, const float* __restrict__ key,
        const float* __restrict__ Wq, const float* __restrict__ Wk,
        u32* __restrict__ scale_bits) {
#pragma clang fp contract(off)
    __shared__ u32 lmax[4];
    if (threadIdx.x < 4) lmax[threadIdx.x] = 0u;
    PROJ_BODY(
        u32 bits = __float_as_uint(fabsf(v));
        __syncthreads();
        atomicMax(&lmax[h], bits);
        __syncthreads();
        if (threadIdx.x < 4 && lmax[threadIdx.x])
            atomicMax(&scale_bits[type * 8 + b * 4 + threadIdx.x], lmax[threadIdx.x]);
    )
}

// Pass 2: recompute identical projection, quantize to int8 (round-half-even).
__global__ __launch_bounds__(256, 2) void proj_quant_kernel(
        const float* __restrict__ query, const float* __restrict__ key,
        const float* __restrict__ Wq, const float* __restrict__ Wk,
        const u32* __restrict__ scale_bits,
        char* __restrict__ q8, char* __restrict__ k8) {
#pragma clang fp contract(off)
    PROJ_BODY(
        float mx = __uint_as_float(scale_bits[type * 8 + b * 4 + h]);
        float scale = (mx + 1e-6f) / 127.0f;
        float r = rintf(v / scale);
        r = fminf(fmaxf(r, -127.f), 127.f);
        (type ? k8 : q8)[(size_t)trow * 32 + o] = (char)(int)r;
    )
}

// ---------------- fused scores + EXACT top-64, register-resident keys ----------------
__global__ __launch_bounds__(256, 4) void score_topk_kernel(
    const char* __restrict__ q8, const char* __restrict__ k8,
    const u32* __restrict__ scale_bits, const float* __restrict__ w,
    int* __restrict__ out) {
#pragma clang fp contract(off)
    __shared__ u64 wmax[2][4];

    const int row = blockIdx.x;  // b*NQ + qi
    const int b = row >> 12;
    const int t = threadIdx.x;
    const int wv = t >> 6;

    const u32* qr = (const u32*)(q8 + (size_t)row * 32);
    u32 qa[8];
#pragma unroll
    for (int j = 0; j < 8; ++j) qa[j] = qr[j];

    float ts[HH], wt[HH];
#pragma unroll
    for (int h = 0; h < HH; ++h) {
        float qs = (__uint_as_float(scale_bits[b * 4 + h]) + 1e-6f) / 127.0f;
        float ks = (__uint_as_float(scale_bits[8 + b * 4 + h]) + 1e-6f) / 127.0f;
        ts[h] = qs * ks;
        wt[h] = w[h];
    }

    const u32* kbase = (const u32*)(k8 + (size_t)b * NK * 32);
    u64 key[32];
#pragma unroll
    for (int i = 0; i < 32; ++i) {
        int n = t + i * 256;
        const u32* kr = kbase + (size_t)n * 8;
        uint4 k0 = *(const uint4*)(kr);
        uint4 k1 = *(const uint4*)(kr + 4);
        float acc = 0.f;
        {
            int s = dot4i8(qa[0], k0.x, 0); s = dot4i8(qa[1], k0.y, s);
            float sf = (float)s * ts[0]; sf = fmaxf(sf, 0.f);
            float prod = sf * wt[0]; acc = acc + prod;
        }
        {
            int s = dot4i8(qa[2], k0.z, 0); s = dot4i8(qa[3], k0.w, s);
            float sf = (float)s * ts[1]; sf = fmaxf(sf, 0.f);
            float prod = sf * wt[1]; acc = acc + prod;
        }
        {
            int s = dot4i8(qa[4], k1.x, 0); s = dot4i8(qa[5], k1.y, s);
            float sf = (float)s * ts[2]; sf = fmaxf(sf, 0.f);
            float prod = sf * wt[2]; acc = acc + prod;
        }
        {
            int s = dot4i8(qa[6], k1.z, 0); s = dot4i8(qa[7], k1.w, s);
            float sf = (float)s * ts[3]; sf = fmaxf(sf, 0.f);
            float prod = sf * wt[3]; acc = acc + prod;
        }
        acc = acc + 0.0f;  // canonicalize -0 -> +0
        u32 u = __float_as_uint(acc);
        u = (u & 0x80000000u) ? ~u : (u | 0x80000000u);
        key[i] = ((u64)u << 32) | (u64)(0xFFFFFFFFu - (u32)n);  // ties: lower index
    }

    u64 lmax = key[0];
#pragma unroll
    for (int i = 1; i < 32; ++i) lmax = key[i] > lmax ? key[i] : lmax;

    for (int r = 0; r < TOPK; ++r) {
        u64 m = lmax;
#pragma unroll
        for (int off = 32; off > 0; off >>= 1) {
            u64 o = __shfl_down(m, off, 64);
            m = o > m ? o : m;
        }
        int p = r & 1;
        if ((t & 63) == 0) wmax[p][wv] = m;
        __syncthreads();
        u64 g0 = wmax[p][0] > wmax[p][1] ? wmax[p][0] : wmax[p][1];
        u64 g1 = wmax[p][2] > wmax[p][3] ? wmax[p][2] : wmax[p][3];
        u64 gm = g0 > g1 ? g0 : g1;
        u32 n = 0xFFFFFFFFu - (u32)gm;
        if (t == 0) out[(size_t)row * TOPK + r] = (int)n;
        if ((int)(n & 255u) == t) {  // owner: clear winner, refresh cached max
            int slot = (int)(n >> 8);
#pragma unroll
            for (int i = 0; i < 32; ++i)
                if (i == slot) key[i] = 0ull;
            lmax = key[0];
#pragma unroll
            for (int i = 1; i < 32; ++i) lmax = key[i] > lmax ? key[i] : lmax;
        }
        // no trailing barrier: next round writes the other wmax buffer
    }
}

extern "C" void kernel_launch(void* const* d_in, const int* in_sizes, int n_in,
                              void* d_out, int out_size, void* d_ws, size_t ws_size,
                              hipStream_t stream) {
    const float* query = (const float*)d_in[0];
    const float* key = (const float*)d_in[1];
    const float* Wq = (const float*)d_in[2];
    const float* Wk = (const float*)d_in[3];
    const float* ow = (const float*)d_in[4];

    char* ws = (char*)d_ws;
    u32* scale_bits = (u32*)ws;
    char* q8 = ws + 1024;
    char* k8 = q8 + BB * NQ * 32;
    int* out = (int*)d_out;

    hipMemsetAsync(scale_bits, 0, 64, stream);

    const int nblocks = (BB * (NQ + NK)) / 16 * 2;  // 3072: 16 rows x 2 o-halves
    proj_absmax_kernel<<<nblocks, 256, 0, stream>>>(query, key, Wq, Wk, scale_bits);
    proj_quant_kernel<<<nblocks, 256, 0, stream>>>(query, key, Wq, Wk, scale_bits, q8, k8);
    score_topk_kernel<<<BB * NQ, 256, 0, stream>>>(q8, k8, scale_bits, ow, out);
}